// Round 3
// baseline (383.109 us; speedup 1.0000x reference)
//
#include <hip/hip_runtime.h>
#include <math.h>

#define BB 8
#define LL 64
#define NP 63          // frame pairs per batch
#define MM 16          // sampled frames
#define HH 112
#define WW 112
#define HW (HH*WW)
#define CIN 3
#define CMID 8
#define COUT 3
#define NTH 448        // 32 rows x 14 col-groups of 8
#define RPB 32         // rows per block (stripe)

// workspace byte offsets
#define WS_SCORES 0        // double[504*4]
#define WS_IDX    16384    // int[128]
#define WS_WT     17408    // float[1176]  score weights [c*7+ky][kx][o=8]
#define WS_WC     22528    // float[588]   combined weights [c*7+ky][kx][o pad4]
#define WS_BIAS2  24960    // float[4]
#define WS_PART   25088    // float[512*6]
#define WS_STATS  37376    // float[6]

#define PD_EPS 1e-6f
#define BN_EPS 1e-5f

// ---------------------------------------------------------------- prep
// transpose score weights for contiguous s_load; build combined 1x1o7x7 weights
__global__ void prep_kernel(const float* __restrict__ cw, const float* __restrict__ cb,
                            const float* __restrict__ bw, char* __restrict__ ws)
{
    float* wT = (float*)(ws + WS_WT);
    float* wc = (float*)(ws + WS_WC);
    float* b2 = (float*)(ws + WS_BIAS2);
    int tid = threadIdx.x;
    for (int i = tid; i < CIN*49*CMID; i += 256) {
        int cky = i / 56, r = i % 56, kx = r / 8, o = r % 8;
        int c = cky / 7, ky = cky % 7;
        wT[i] = cw[((o*CIN + c)*7 + ky)*7 + kx];
    }
    for (int i = tid; i < CIN*49; i += 256) {
        int c = i / 49, ky = (i / 7) % 7, kx = i % 7;
        for (int o = 0; o < COUT; ++o) {
            float s = 0.f;
            for (int m = 0; m < CMID; ++m)
                s += bw[o*CMID + m] * cw[((m*CIN + c)*7 + ky)*7 + kx];
            wc[(c*7 + ky)*28 + kx*4 + o] = s;
        }
        wc[(c*7 + ky)*28 + kx*4 + 3] = 0.f;
    }
    if (tid < COUT) {
        float s = 0.f;
        for (int m = 0; m < CMID; ++m) s += bw[tid*CMID + m] * cb[m];
        b2[tid] = s;
    }
}

// ---------------------------------------------------------------- scores
// one block = one 32-row stripe of one pair. Tile read direct from global
// (L1/L2-resident), weights via s_load (lgkmcnt has no ds_read to collide with).
// No LDS staging, no barriers in the main loop.
__global__ __launch_bounds__(NTH, 3) void score_kernel(
    const float* __restrict__ x, char* __restrict__ ws)
{
    const float* wT = (const float*)(ws + WS_WT);
    double* scores  = (double*)(ws + WS_SCORES);
    __shared__ double sred[7];

    int B = blockIdx.x;                       // 2016 blocks
    int work = (B & 7) * 252 + (B >> 3);      // XCD-chunked swizzle (2016%8==0)
    int pair = work >> 2, q = work & 3;
    int b = pair / NP, t = pair % NP;
    const float* x0 = x + (size_t)(b*LL + t) * (CIN*HW);
    const float* x1 = x0 + CIN*HW;

    int tid = threadIdx.x;
    int iy = tid / 14, xg = tid % 14, xb = xg * 8;
    int orow = q*RPB + iy;

    double dacc = 0.0;
    if (orow < HH) {
        float acc[8][8];
        #pragma unroll
        for (int p = 0; p < 8; ++p)
            #pragma unroll
            for (int o = 0; o < 8; ++o) acc[p][o] = 0.f;

        #pragma unroll 1
        for (int c = 0; c < CIN; ++c) {
            const float* p0 = x0 + c*HW;
            const float* p1 = x1 + c*HW;
            #pragma unroll 2
            for (int ky = 0; ky < 7; ++ky) {
                int r = orow + ky - 3;
                const float* wrow = wT + (c*7 + ky)*56;   // uniform -> s_load
                if ((unsigned)r < HH) {
                    const float* r0 = p0 + r*WW;
                    const float* r1 = p1 + r*WW;
                    float v[16];
                    if (xg == 0) {
                        float4 a0 = *(const float4*)(r0);
                        float4 a1 = *(const float4*)(r0 + 4);
                        float4 a2 = *(const float4*)(r0 + 8);
                        float4 c0 = *(const float4*)(r1);
                        float4 c1 = *(const float4*)(r1 + 4);
                        float4 c2 = *(const float4*)(r1 + 8);
                        v[0]=0.f; v[1]=0.f; v[2]=0.f; v[3]=0.f;
                        v[4]=a0.x-c0.x; v[5]=a0.y-c0.y; v[6]=a0.z-c0.z; v[7]=a0.w-c0.w;
                        v[8]=a1.x-c1.x; v[9]=a1.y-c1.y; v[10]=a1.z-c1.z; v[11]=a1.w-c1.w;
                        v[12]=a2.x-c2.x; v[13]=a2.y-c2.y; v[14]=a2.z-c2.z; v[15]=a2.w-c2.w;
                    } else if (xg == 13) {
                        float4 a0 = *(const float4*)(r0 + 100);
                        float4 a1 = *(const float4*)(r0 + 104);
                        float4 a2 = *(const float4*)(r0 + 108);
                        float4 c0 = *(const float4*)(r1 + 100);
                        float4 c1 = *(const float4*)(r1 + 104);
                        float4 c2 = *(const float4*)(r1 + 108);
                        v[0]=a0.x-c0.x; v[1]=a0.y-c0.y; v[2]=a0.z-c0.z; v[3]=a0.w-c0.w;
                        v[4]=a1.x-c1.x; v[5]=a1.y-c1.y; v[6]=a1.z-c1.z; v[7]=a1.w-c1.w;
                        v[8]=a2.x-c2.x; v[9]=a2.y-c2.y; v[10]=a2.z-c2.z; v[11]=a2.w-c2.w;
                        v[12]=0.f; v[13]=0.f; v[14]=0.f; v[15]=0.f;
                    } else {
                        const float* s0 = r0 + xb - 4;
                        const float* s1 = r1 + xb - 4;
                        float4 a0 = *(const float4*)(s0);
                        float4 a1 = *(const float4*)(s0 + 4);
                        float4 a2 = *(const float4*)(s0 + 8);
                        float4 a3 = *(const float4*)(s0 + 12);
                        float4 c0 = *(const float4*)(s1);
                        float4 c1 = *(const float4*)(s1 + 4);
                        float4 c2 = *(const float4*)(s1 + 8);
                        float4 c3 = *(const float4*)(s1 + 12);
                        v[0]=a0.x-c0.x; v[1]=a0.y-c0.y; v[2]=a0.z-c0.z; v[3]=a0.w-c0.w;
                        v[4]=a1.x-c1.x; v[5]=a1.y-c1.y; v[6]=a1.z-c1.z; v[7]=a1.w-c1.w;
                        v[8]=a2.x-c2.x; v[9]=a2.y-c2.y; v[10]=a2.z-c2.z; v[11]=a2.w-c2.w;
                        v[12]=a3.x-c3.x; v[13]=a3.y-c3.y; v[14]=a3.z-c3.z; v[15]=a3.w-c3.w;
                    }
                    #pragma unroll
                    for (int kx = 0; kx < 7; ++kx) {
                        #pragma unroll
                        for (int o = 0; o < 8; ++o) {
                            float wv = wrow[kx*8 + o];    // SGPR operand
                            #pragma unroll
                            for (int p = 0; p < 8; ++p)
                                acc[p][o] += wv * v[p + kx + 1];
                        }
                    }
                }
            }
        }
        #pragma unroll
        for (int p = 0; p < 8; ++p) {
            float ss = 0.f;
            #pragma unroll
            for (int o = 0; o < 8; ++o) {
                float d = acc[p][o] + PD_EPS;
                ss += d*d;
            }
            dacc += (double)sqrtf(ss);
        }
    }

    #pragma unroll
    for (int off = 32; off > 0; off >>= 1)
        dacc += __shfl_down(dacc, off, 64);
    int wid = tid >> 6, lane = tid & 63;
    if (lane == 0) sred[wid] = dacc;
    __syncthreads();
    if (tid == 0) {
        double s = 0.0;
        for (int w = 0; w < 7; ++w) s += sred[w];
        scores[pair*4 + q] = s;
    }
}

// ---------------------------------------------------------------- sampling
__global__ void sample_kernel(char* __restrict__ ws)
{
    __shared__ double cum[BB][NP];
    const double* scores = (const double*)(ws + WS_SCORES);
    int* idxs = (int*)(ws + WS_IDX);
    int tid = threadIdx.x;                // 128
    if (tid < BB) {
        double tot = 0.0;
        for (int t = 0; t < NP; ++t) {
            const double* sp = scores + (tid*NP + t)*4;
            tot += sqrt(sp[0] + sp[1] + sp[2] + sp[3]);
        }
        double run = 0.0;
        for (int t = 0; t < NP; ++t) {
            const double* sp = scores + (tid*NP + t)*4;
            run += sqrt(sp[0] + sp[1] + sp[2] + sp[3]) / tot;
            cum[tid][t] = run;
        }
    }
    __syncthreads();
    {
        int b = tid / MM, m = tid % MM;
        double target = (double)((float)m / 15.f);
        int best = 0;
        double bv = fabs(cum[b][0] - target);
        for (int t = 1; t < NP; ++t) {
            double v = fabs(cum[b][t] - target);
            if (v < bv) { bv = v; best = t; }   // strict: first min wins
        }
        idxs[tid] = best;
    }
}

// ---------------------------------------------------------------- resblock conv
// one block = one 32-row stripe of one selected frame; combined 7x7 3->3,
// direct-global tile, s_load weights; y -> d_out + BN partials.
__global__ __launch_bounds__(NTH, 3) void resconv_kernel(
    const float* __restrict__ x, char* __restrict__ ws, float* __restrict__ out)
{
    const float* wc    = (const float*)(ws + WS_WC);
    const float* bias2 = (const float*)(ws + WS_BIAS2);
    const int* idxs    = (const int*)(ws + WS_IDX);
    float* part        = (float*)(ws + WS_PART);
    __shared__ double sred[7][6];

    int B = blockIdx.x;                       // 512 blocks
    int work = (B & 7) * 64 + (B >> 3);
    int n = work >> 2, q = work & 3;
    int b = n / MM;
    int l = idxs[n];
    const float* src = x + (size_t)(b*LL + l) * (CIN*HW);
    float* ybase = out + (size_t)n * (COUT*HW);

    int tid = threadIdx.x;
    int iy = tid / 14, xg = tid % 14, xb = xg * 8;
    int orow = q*RPB + iy;

    double sm0=0, sm1=0, sm2=0, sq0=0, sq1=0, sq2=0;

    if (orow < HH) {
        float acc[8][3];
        #pragma unroll
        for (int p = 0; p < 8; ++p) { acc[p][0]=0.f; acc[p][1]=0.f; acc[p][2]=0.f; }

        #pragma unroll 1
        for (int c = 0; c < CIN; ++c) {
            const float* p0 = src + c*HW;
            #pragma unroll 2
            for (int ky = 0; ky < 7; ++ky) {
                int r = orow + ky - 3;
                const float* wrow = wc + (c*7 + ky)*28;   // uniform -> s_load
                if ((unsigned)r < HH) {
                    const float* r0 = p0 + r*WW;
                    float v[16];
                    if (xg == 0) {
                        float4 a0 = *(const float4*)(r0);
                        float4 a1 = *(const float4*)(r0 + 4);
                        float4 a2 = *(const float4*)(r0 + 8);
                        v[0]=0.f; v[1]=0.f; v[2]=0.f; v[3]=0.f;
                        v[4]=a0.x; v[5]=a0.y; v[6]=a0.z; v[7]=a0.w;
                        v[8]=a1.x; v[9]=a1.y; v[10]=a1.z; v[11]=a1.w;
                        v[12]=a2.x; v[13]=a2.y; v[14]=a2.z; v[15]=a2.w;
                    } else if (xg == 13) {
                        float4 a0 = *(const float4*)(r0 + 100);
                        float4 a1 = *(const float4*)(r0 + 104);
                        float4 a2 = *(const float4*)(r0 + 108);
                        v[0]=a0.x; v[1]=a0.y; v[2]=a0.z; v[3]=a0.w;
                        v[4]=a1.x; v[5]=a1.y; v[6]=a1.z; v[7]=a1.w;
                        v[8]=a2.x; v[9]=a2.y; v[10]=a2.z; v[11]=a2.w;
                        v[12]=0.f; v[13]=0.f; v[14]=0.f; v[15]=0.f;
                    } else {
                        const float* s0 = r0 + xb - 4;
                        float4 a0 = *(const float4*)(s0);
                        float4 a1 = *(const float4*)(s0 + 4);
                        float4 a2 = *(const float4*)(s0 + 8);
                        float4 a3 = *(const float4*)(s0 + 12);
                        v[0]=a0.x; v[1]=a0.y; v[2]=a0.z; v[3]=a0.w;
                        v[4]=a1.x; v[5]=a1.y; v[6]=a1.z; v[7]=a1.w;
                        v[8]=a2.x; v[9]=a2.y; v[10]=a2.z; v[11]=a2.w;
                        v[12]=a3.x; v[13]=a3.y; v[14]=a3.z; v[15]=a3.w;
                    }
                    #pragma unroll
                    for (int kx = 0; kx < 7; ++kx) {
                        #pragma unroll
                        for (int o = 0; o < 3; ++o) {
                            float wv = wrow[kx*4 + o];
                            #pragma unroll
                            for (int p = 0; p < 8; ++p)
                                acc[p][o] += wv * v[p + kx + 1];
                        }
                    }
                }
            }
        }

        float bb0 = bias2[0], bb1 = bias2[1], bb2 = bias2[2];
        float4 y0, y1; float* py0 = (float*)&y0; float* py1 = (float*)&y1;
        #pragma unroll
        for (int p = 0; p < 4; ++p) {
            float a = acc[p][0] + bb0;   py0[p] = a; sm0 += a; sq0 += (double)a*a;
            float d = acc[p+4][0] + bb0; py1[p] = d; sm0 += d; sq0 += (double)d*d;
        }
        *(float4*)(ybase + 0*HW + orow*WW + xb)     = y0;
        *(float4*)(ybase + 0*HW + orow*WW + xb + 4) = y1;
        #pragma unroll
        for (int p = 0; p < 4; ++p) {
            float a = acc[p][1] + bb1;   py0[p] = a; sm1 += a; sq1 += (double)a*a;
            float d = acc[p+4][1] + bb1; py1[p] = d; sm1 += d; sq1 += (double)d*d;
        }
        *(float4*)(ybase + 1*HW + orow*WW + xb)     = y0;
        *(float4*)(ybase + 1*HW + orow*WW + xb + 4) = y1;
        #pragma unroll
        for (int p = 0; p < 4; ++p) {
            float a = acc[p][2] + bb2;   py0[p] = a; sm2 += a; sq2 += (double)a*a;
            float d = acc[p+4][2] + bb2; py1[p] = d; sm2 += d; sq2 += (double)d*d;
        }
        *(float4*)(ybase + 2*HW + orow*WW + xb)     = y0;
        *(float4*)(ybase + 2*HW + orow*WW + xb + 4) = y1;
    }

    double vals[6] = {sm0, sm1, sm2, sq0, sq1, sq2};
    #pragma unroll
    for (int j = 0; j < 6; ++j) {
        #pragma unroll
        for (int off = 32; off > 0; off >>= 1)
            vals[j] += __shfl_down(vals[j], off, 64);
    }
    int wid = tid >> 6, lane = tid & 63;
    if (lane == 0) {
        #pragma unroll
        for (int j = 0; j < 6; ++j) sred[wid][j] = vals[j];
    }
    __syncthreads();
    if (tid < 6) {
        double s = 0.0;
        for (int w = 0; w < 7; ++w) s += sred[w][tid];
        part[B*6 + tid] = (float)s;
    }
}

// ---------------------------------------------------------------- stats reduce
__global__ void statreduce_kernel(char* __restrict__ ws)
{
    const float* part = (const float*)(ws + WS_PART);
    float* stats = (float*)(ws + WS_STATS);
    int tid = threadIdx.x;            // 384: 6 cols x 64 lanes
    int j = tid >> 6, lane = tid & 63;
    double s = 0.0;
    for (int n = lane; n < 512; n += 64) s += (double)part[n*6 + j];
    #pragma unroll
    for (int off = 32; off > 0; off >>= 1)
        s += __shfl_down(s, off, 64);
    if (lane == 0) stats[j] = (float)s;
}

// ---------------------------------------------------------------- finalize
__global__ __launch_bounds__(256) void finalize_kernel(
    const float* __restrict__ x, const float* __restrict__ gamma,
    const float* __restrict__ beta, const char* __restrict__ ws,
    float* __restrict__ out)
{
    const float* stats = (const float*)(ws + WS_STATS);
    const int* idxs    = (const int*)(ws + WS_IDX);
    int i4 = blockIdx.x * 256 + threadIdx.x;
    int i  = i4 * 4;
    int n  = i / (COUT*HW);
    int c  = (i / HW) % COUT;
    int hw = i % HW;
    int b  = n / MM;
    int l  = idxs[n];
    const float Ninv = 1.f / (float)(BB*MM*HW);
    float mean  = stats[c] * Ninv;
    float var   = stats[3+c] * Ninv - mean*mean;
    float scale = gamma[c] / sqrtf(var + BN_EPS);
    float shift = beta[c] - mean*scale;
    float4 y  = *(const float4*)&out[i];
    float4 xv = *(const float4*)&x[((size_t)(b*LL + l)*CIN + c)*HW + hw];
    float4 r;
    r.x = xv.x + fmaxf(y.x*scale + shift, 0.f);
    r.y = xv.y + fmaxf(y.y*scale + shift, 0.f);
    r.z = xv.z + fmaxf(y.z*scale + shift, 0.f);
    r.w = xv.w + fmaxf(y.w*scale + shift, 0.f);
    *(float4*)&out[i] = r;
}

// ---------------------------------------------------------------- launch
extern "C" void kernel_launch(void* const* d_in, const int* in_sizes, int n_in,
                              void* d_out, int out_size, void* d_ws, size_t ws_size,
                              hipStream_t stream)
{
    const float* x       = (const float*)d_in[0];
    const float* conv_w  = (const float*)d_in[1];
    const float* conv_b  = (const float*)d_in[2];
    const float* bneck_w = (const float*)d_in[3];
    const float* gamma   = (const float*)d_in[4];
    const float* beta    = (const float*)d_in[5];
    float* out = (float*)d_out;
    char* ws   = (char*)d_ws;

    prep_kernel<<<1, 256, 0, stream>>>(conv_w, conv_b, bneck_w, ws);
    score_kernel<<<BB*NP*4, NTH, 0, stream>>>(x, ws);
    sample_kernel<<<1, 128, 0, stream>>>(ws);
    resconv_kernel<<<BB*MM*4, NTH, 0, stream>>>(x, ws, out);
    statreduce_kernel<<<1, 384, 0, stream>>>(ws);
    int total4 = (BB*MM*COUT*HW) / 4;
    finalize_kernel<<<total4 / 256, 256, 0, stream>>>(x, gamma, beta, ws, out);
}

// Round 4
// 285.085 us; speedup vs baseline: 1.3438x; 1.3438x over previous
//
#include <hip/hip_runtime.h>
#include <math.h>

#define BB 8
#define LL 64
#define NP 63          // frame pairs per batch
#define MM 16          // sampled frames
#define HH 112
#define WW 112
#define HW (HH*WW)
#define CIN 3
#define CMID 8
#define COUT 3
#define TH 16          // stripe rows
#define TSTRIDE 120    // WW + 8 pad
#define NTH 448        // 16 rows x 28 col-groups of 4 px
#define STAGE_ELEMS (CIN*(TH+6)*TSTRIDE)   // 7920

// workspace byte offsets
#define WS_SCORES 0        // double[504*2]
#define WS_IDX    16384    // int[128]
#define WS_WT     17408    // float[1176]  score weights [c*7+ky][kx][o=8]
#define WS_WC     22528    // float[588]   combined weights [c*7+ky][kx][o pad4]
#define WS_BIAS2  24960    // float[4]
#define WS_PART   25088    // float[256*6]
#define WS_STATS  37376    // float[6]

#define PD_EPS 1e-6f
#define BN_EPS 1e-5f

// ---------------------------------------------------------------- prep
// transpose score weights contiguous per (c,ky); build combined 1x1o7x7 weights
__global__ void prep_kernel(const float* __restrict__ cw, const float* __restrict__ cb,
                            const float* __restrict__ bw, char* __restrict__ ws)
{
    float* wT = (float*)(ws + WS_WT);
    float* wc = (float*)(ws + WS_WC);
    float* b2 = (float*)(ws + WS_BIAS2);
    int tid = threadIdx.x;
    for (int i = tid; i < CIN*49*CMID; i += 256) {
        int cky = i / 56, r = i % 56, kx = r / 8, o = r % 8;
        int c = cky / 7, ky = cky % 7;
        wT[i] = cw[((o*CIN + c)*7 + ky)*7 + kx];
    }
    for (int i = tid; i < CIN*49; i += 256) {
        int c = i / 49, ky = (i / 7) % 7, kx = i % 7;
        for (int o = 0; o < COUT; ++o) {
            float s = 0.f;
            for (int m = 0; m < CMID; ++m)
                s += bw[o*CMID + m] * cw[((m*CIN + c)*7 + ky)*7 + kx];
            wc[(c*7 + ky)*28 + kx*4 + o] = s;
        }
        wc[(c*7 + ky)*28 + kx*4 + 3] = 0.f;
    }
    if (tid < COUT) {
        float s = 0.f;
        for (int m = 0; m < CMID; ++m) s += bw[tid*CMID + m] * cb[m];
        b2[tid] = s;
    }
}

// ---------------------------------------------------------------- scores
// 2 blocks per pair (stripes 0-3 / 4-6). LDS tile for the diff image;
// weights via CONTIGUOUS uniform loads from transposed table -> s_load_dwordx16
// -> SGPR FMA operands (no LDS weight traffic, no vmem in inner loop).
__global__ __launch_bounds__(NTH) void score_kernel(
    const float* __restrict__ x, char* __restrict__ ws)
{
    __shared__ __align__(16) float tile[CIN][TH+6][TSTRIDE];
    __shared__ double sred[7];
    const float* wT = (const float*)(ws + WS_WT);
    double* scores  = (double*)(ws + WS_SCORES);

    int B = blockIdx.x;                        // 1008 blocks, 1008%8==0
    int work = (B & 7) * 126 + (B >> 3);       // XCD-chunked swizzle
    int pair = work >> 1, half = work & 1;
    int b = pair / NP, t = pair % NP;
    const float* x0 = x + (size_t)(b*LL + t) * (CIN*HW);
    const float* x1 = x0 + CIN*HW;

    int tid = threadIdx.x;
    int iy = tid / 28;
    int xb = (tid % 28) * 4;
    int s0 = half * 4, s1 = half ? 7 : 4;

    double dacc = 0.0;

    for (int s = s0; s < s1; ++s) {
        __syncthreads();
        int base = s*TH - 3;
        for (int i = tid; i < STAGE_ELEMS; i += NTH) {
            int c  = i / ((TH+6)*TSTRIDE);
            int r  = (i / TSTRIDE) % (TH+6);
            int cc = i % TSTRIDE;
            int gr = base + r, gc = cc - 3;
            float v = 0.f;
            if (gr >= 0 && gr < HH && gc >= 0 && gc < WW) {
                int off = c*HW + gr*WW + gc;
                v = x0[off] - x1[off];
            }
            tile[c][r][cc] = v;
        }
        __syncthreads();

        float acc[4][8];
        #pragma unroll
        for (int p = 0; p < 4; ++p)
            #pragma unroll
            for (int o = 0; o < 8; ++o) acc[p][o] = 0.f;

        #pragma unroll 1
        for (int cky = 0; cky < 21; ++cky) {
            int c = cky / 7, ky = cky % 7;
            const float* tr = &tile[c][iy + ky][xb];
            float v[12];
            *(float4*)&v[0] = *(const float4*)&tr[0];
            *(float4*)&v[4] = *(const float4*)&tr[4];
            *(float4*)&v[8] = *(const float4*)&tr[8];
            const float* wrow = wT + cky*56;          // uniform, contiguous
            #pragma unroll
            for (int kx = 0; kx < 7; ++kx) {
                #pragma unroll
                for (int o = 0; o < 8; ++o) {
                    float wv = wrow[kx*8 + o];        // s_load -> SGPR
                    #pragma unroll
                    for (int p = 0; p < 4; ++p)
                        acc[p][o] += wv * v[p + kx];
                }
            }
        }

        #pragma unroll
        for (int p = 0; p < 4; ++p) {
            float ss = 0.f;
            #pragma unroll
            for (int o = 0; o < 8; ++o) {
                float d = acc[p][o] + PD_EPS;
                ss += d*d;
            }
            dacc += (double)sqrtf(ss);
        }
    }

    #pragma unroll
    for (int off = 32; off > 0; off >>= 1)
        dacc += __shfl_down(dacc, off, 64);
    int wid = tid >> 6, lane = tid & 63;
    if (lane == 0) sred[wid] = dacc;
    __syncthreads();
    if (tid == 0) {
        double ssum = 0.0;
        for (int w = 0; w < 7; ++w) ssum += sred[w];
        scores[pair*2 + half] = ssum;
    }
}

// ---------------------------------------------------------------- sampling
__global__ void sample_kernel(char* __restrict__ ws)
{
    __shared__ double cum[BB][NP];
    const double* scores = (const double*)(ws + WS_SCORES);
    int* idxs = (int*)(ws + WS_IDX);
    int tid = threadIdx.x;                // 128
    if (tid < BB) {
        double tot = 0.0;
        for (int t = 0; t < NP; ++t)
            tot += sqrt(scores[(tid*NP + t)*2] + scores[(tid*NP + t)*2 + 1]);
        double run = 0.0;
        for (int t = 0; t < NP; ++t) {
            run += sqrt(scores[(tid*NP + t)*2] + scores[(tid*NP + t)*2 + 1]) / tot;
            cum[tid][t] = run;
        }
    }
    __syncthreads();
    {
        int b = tid / MM, m = tid % MM;
        double target = (double)((float)m / 15.f);
        int best = 0;
        double bv = fabs(cum[b][0] - target);
        for (int t = 1; t < NP; ++t) {
            double v = fabs(cum[b][t] - target);
            if (v < bv) { bv = v; best = t; }   // strict: first min wins
        }
        idxs[tid] = best;
    }
}

// ---------------------------------------------------------------- resblock conv
// 2 blocks per selected frame; LDS tile + SGPR weights; y -> d_out + BN partials
__global__ __launch_bounds__(NTH) void resconv_kernel(
    const float* __restrict__ x, char* __restrict__ ws, float* __restrict__ out)
{
    __shared__ __align__(16) float tile[CIN][TH+6][TSTRIDE];
    __shared__ double sred[7][6];

    const float* wc    = (const float*)(ws + WS_WC);
    const float* bias2 = (const float*)(ws + WS_BIAS2);
    const int* idxs    = (const int*)(ws + WS_IDX);
    float* part        = (float*)(ws + WS_PART);

    int B = blockIdx.x;                        // 256 blocks
    int work = (B & 7) * 32 + (B >> 3);
    int n = work >> 1, half = work & 1;
    int b = n / MM;
    int l = idxs[n];
    const float* src = x + (size_t)(b*LL + l) * (CIN*HW);
    float* ybase = out + (size_t)n * (COUT*HW);

    int tid = threadIdx.x;
    int iy = tid / 28;
    int xb = (tid % 28) * 4;
    int s0 = half * 4, s1 = half ? 7 : 4;

    float bb0 = bias2[0], bb1 = bias2[1], bb2 = bias2[2];
    double sm0=0, sm1=0, sm2=0, sq0=0, sq1=0, sq2=0;

    for (int s = s0; s < s1; ++s) {
        __syncthreads();
        int base = s*TH - 3;
        for (int i = tid; i < STAGE_ELEMS; i += NTH) {
            int c  = i / ((TH+6)*TSTRIDE);
            int r  = (i / TSTRIDE) % (TH+6);
            int cc = i % TSTRIDE;
            int gr = base + r, gc = cc - 3;
            float v = 0.f;
            if (gr >= 0 && gr < HH && gc >= 0 && gc < WW)
                v = src[c*HW + gr*WW + gc];
            tile[c][r][cc] = v;
        }
        __syncthreads();

        float acc[4][3];
        #pragma unroll
        for (int p = 0; p < 4; ++p) { acc[p][0]=0.f; acc[p][1]=0.f; acc[p][2]=0.f; }

        #pragma unroll 1
        for (int cky = 0; cky < 21; ++cky) {
            int c = cky / 7, ky = cky % 7;
            const float* tr = &tile[c][iy + ky][xb];
            float v[12];
            *(float4*)&v[0] = *(const float4*)&tr[0];
            *(float4*)&v[4] = *(const float4*)&tr[4];
            *(float4*)&v[8] = *(const float4*)&tr[8];
            const float* wrow = wc + cky*28;          // uniform, contiguous
            #pragma unroll
            for (int kx = 0; kx < 7; ++kx) {
                #pragma unroll
                for (int o = 0; o < 3; ++o) {
                    float wv = wrow[kx*4 + o];        // s_load -> SGPR
                    #pragma unroll
                    for (int p = 0; p < 4; ++p)
                        acc[p][o] += wv * v[p + kx];
                }
            }
        }

        int gy = s*TH + iy;
        float4 yv; float* pyv = (float*)&yv;
        #pragma unroll
        for (int p = 0; p < 4; ++p) {
            float val = acc[p][0] + bb0;
            pyv[p] = val; sm0 += val; sq0 += (double)val*val;
        }
        *(float4*)&ybase[0*HW + gy*WW + xb] = yv;
        #pragma unroll
        for (int p = 0; p < 4; ++p) {
            float val = acc[p][1] + bb1;
            pyv[p] = val; sm1 += val; sq1 += (double)val*val;
        }
        *(float4*)&ybase[1*HW + gy*WW + xb] = yv;
        #pragma unroll
        for (int p = 0; p < 4; ++p) {
            float val = acc[p][2] + bb2;
            pyv[p] = val; sm2 += val; sq2 += (double)val*val;
        }
        *(float4*)&ybase[2*HW + gy*WW + xb] = yv;
    }

    double vals[6] = {sm0, sm1, sm2, sq0, sq1, sq2};
    #pragma unroll
    for (int j = 0; j < 6; ++j) {
        #pragma unroll
        for (int off = 32; off > 0; off >>= 1)
            vals[j] += __shfl_down(vals[j], off, 64);
    }
    int wid = tid >> 6, lane = tid & 63;
    if (lane == 0) {
        #pragma unroll
        for (int j = 0; j < 6; ++j) sred[wid][j] = vals[j];
    }
    __syncthreads();
    if (tid < 6) {
        double s = 0.0;
        for (int w = 0; w < 7; ++w) s += sred[w][tid];
        part[B*6 + tid] = (float)s;
    }
}

// ---------------------------------------------------------------- stats reduce
__global__ void statreduce_kernel(char* __restrict__ ws)
{
    const float* part = (const float*)(ws + WS_PART);
    float* stats = (float*)(ws + WS_STATS);
    int tid = threadIdx.x;            // 384: 6 cols x 64 lanes
    int j = tid >> 6, lane = tid & 63;
    double s = 0.0;
    for (int n = lane; n < 256; n += 64) s += (double)part[n*6 + j];
    #pragma unroll
    for (int off = 32; off > 0; off >>= 1)
        s += __shfl_down(s, off, 64);
    if (lane == 0) stats[j] = (float)s;
}

// ---------------------------------------------------------------- finalize
__global__ __launch_bounds__(256) void finalize_kernel(
    const float* __restrict__ x, const float* __restrict__ gamma,
    const float* __restrict__ beta, const char* __restrict__ ws,
    float* __restrict__ out)
{
    const float* stats = (const float*)(ws + WS_STATS);
    const int* idxs    = (const int*)(ws + WS_IDX);
    int i4 = blockIdx.x * 256 + threadIdx.x;
    int i  = i4 * 4;
    int n  = i / (COUT*HW);
    int c  = (i / HW) % COUT;
    int hw = i % HW;
    int b  = n / MM;
    int l  = idxs[n];
    const float Ninv = 1.f / (float)(BB*MM*HW);
    float mean  = stats[c] * Ninv;
    float var   = stats[3+c] * Ninv - mean*mean;
    float scale = gamma[c] / sqrtf(var + BN_EPS);
    float shift = beta[c] - mean*scale;
    float4 y  = *(const float4*)&out[i];
    float4 xv = *(const float4*)&x[((size_t)(b*LL + l)*CIN + c)*HW + hw];
    float4 r;
    r.x = xv.x + fmaxf(y.x*scale + shift, 0.f);
    r.y = xv.y + fmaxf(y.y*scale + shift, 0.f);
    r.z = xv.z + fmaxf(y.z*scale + shift, 0.f);
    r.w = xv.w + fmaxf(y.w*scale + shift, 0.f);
    *(float4*)&out[i] = r;
}

// ---------------------------------------------------------------- launch
extern "C" void kernel_launch(void* const* d_in, const int* in_sizes, int n_in,
                              void* d_out, int out_size, void* d_ws, size_t ws_size,
                              hipStream_t stream)
{
    const float* x       = (const float*)d_in[0];
    const float* conv_w  = (const float*)d_in[1];
    const float* conv_b  = (const float*)d_in[2];
    const float* bneck_w = (const float*)d_in[3];
    const float* gamma   = (const float*)d_in[4];
    const float* beta    = (const float*)d_in[5];
    float* out = (float*)d_out;
    char* ws   = (char*)d_ws;

    prep_kernel<<<1, 256, 0, stream>>>(conv_w, conv_b, bneck_w, ws);
    score_kernel<<<BB*NP*2, NTH, 0, stream>>>(x, ws);
    sample_kernel<<<1, 128, 0, stream>>>(ws);
    resconv_kernel<<<BB*MM*2, NTH, 0, stream>>>(x, ws, out);
    statreduce_kernel<<<1, 384, 0, stream>>>(ws);
    int total4 = (BB*MM*COUT*HW) / 4;
    finalize_kernel<<<total4 / 256, 256, 0, stream>>>(x, gamma, beta, ws, out);
}

// Round 5
// 244.631 us; speedup vs baseline: 1.5661x; 1.1654x over previous
//
#include <hip/hip_runtime.h>
#include <math.h>

#define BB 8
#define LL 64
#define NP 63          // frame pairs per batch
#define MM 16          // sampled frames
#define HH 112
#define WW 112
#define HW (HH*WW)
#define CIN 3
#define CMID 8
#define COUT 3
#define TH 16          // stripe rows
#define TSTRIDE 120    // WW + 8 pad
#define NTH 448        // 16 rows x 28 col-groups of 4 px
#define STAGE_ELEMS (CIN*(TH+6)*TSTRIDE)   // 7920
#define NPREF 18                            // ceil(7920/448)

// workspace byte offsets
#define WS_SCORES 0        // double[504*2]
#define WS_IDX    16384    // int[128]
#define WS_WT     17408    // float[1176]  score weights [c*7+ky][kx][o=8]
#define WS_WC     22528    // float[588]   combined weights [c*7+ky][kx][o pad4]
#define WS_BIAS2  24960    // float[4]
#define WS_PART   25088    // float[256*6]
#define WS_STATS  37376    // float[6]

#define PD_EPS 1e-6f
#define BN_EPS 1e-5f

// ---------------------------------------------------------------- prep
__global__ void prep_kernel(const float* __restrict__ cw, const float* __restrict__ cb,
                            const float* __restrict__ bw, char* __restrict__ ws)
{
    float* wT = (float*)(ws + WS_WT);
    float* wc = (float*)(ws + WS_WC);
    float* b2 = (float*)(ws + WS_BIAS2);
    int tid = threadIdx.x;
    for (int i = tid; i < CIN*49*CMID; i += 256) {
        int cky = i / 56, r = i % 56, kx = r / 8, o = r % 8;
        int c = cky / 7, ky = cky % 7;
        wT[i] = cw[((o*CIN + c)*7 + ky)*7 + kx];
    }
    for (int i = tid; i < CIN*49; i += 256) {
        int c = i / 49, ky = (i / 7) % 7, kx = i % 7;
        for (int o = 0; o < COUT; ++o) {
            float s = 0.f;
            for (int m = 0; m < CMID; ++m)
                s += bw[o*CMID + m] * cw[((m*CIN + c)*7 + ky)*7 + kx];
            wc[(c*7 + ky)*28 + kx*4 + o] = s;
        }
        wc[(c*7 + ky)*28 + kx*4 + 3] = 0.f;
    }
    if (tid < COUT) {
        float s = 0.f;
        for (int m = 0; m < CMID; ++m) s += bw[tid*CMID + m] * cb[m];
        b2[tid] = s;
    }
}

// prefetch next stripe's diff elements into registers (issue-early)
#define PREF_DIFF(SS) do { int sbase = (SS)*TH - 3;                          \
    _Pragma("unroll")                                                        \
    for (int k = 0; k < NPREF; ++k) {                                        \
        int i = tid + k*NTH;                                                 \
        float va = 0.f, vb = 0.f;                                            \
        if (i < STAGE_ELEMS) {                                               \
            int c  = i / ((TH+6)*TSTRIDE);                                   \
            int rem = i - c*((TH+6)*TSTRIDE);                                \
            int r  = rem / TSTRIDE;                                          \
            int cc = rem - r*TSTRIDE;                                        \
            int gr = sbase + r, gc = cc - 3;                                 \
            if ((unsigned)gr < HH && (unsigned)gc < WW) {                    \
                int off = c*HW + gr*WW + gc;                                 \
                va = x0[off]; vb = x1[off];                                  \
            }                                                                \
        }                                                                    \
        pa[k] = va; pb[k] = vb;                                              \
    }                                                                        \
} while (0)

#define WRITE_DIFF(BUF) do {                                                 \
    float* dst = (float*)tile[BUF];                                          \
    _Pragma("unroll")                                                        \
    for (int k = 0; k < NPREF; ++k) {                                        \
        int i = tid + k*NTH;                                                 \
        if (i < STAGE_ELEMS) dst[i] = pa[k] - pb[k];                         \
    }                                                                        \
} while (0)

// ---------------------------------------------------------------- scores
// 2 blocks per pair (stripes 0-3 / 4-6). Double-buffered LDS diff tile with
// register prefetch: loads for stripe s+1 issue BEFORE the FMA phase of s,
// regs->LDS write after it (vmcnt drain hidden under compute). One barrier
// per stripe. Weights via contiguous uniform s_load -> SGPR FMA operands.
__global__ __launch_bounds__(NTH, 4) void score_kernel(
    const float* __restrict__ x, char* __restrict__ ws)
{
    __shared__ __align__(16) float tile[2][CIN][TH+6][TSTRIDE];  // 63360 B
    __shared__ double sred[7];
    const float* wT = (const float*)(ws + WS_WT);
    double* scores  = (double*)(ws + WS_SCORES);

    int B = blockIdx.x;                        // 1008 blocks, 1008%8==0
    int work = (B & 7) * 126 + (B >> 3);       // XCD-chunked swizzle
    int pair = work >> 1, half = work & 1;
    int b = pair / NP, t = pair % NP;
    const float* x0 = x + (size_t)(b*LL + t) * (CIN*HW);
    const float* x1 = x0 + CIN*HW;

    int tid = threadIdx.x;
    int iy = tid / 28;
    int xb = (tid % 28) * 4;
    int s0 = half * 4, s1 = half ? 7 : 4;

    float pa[NPREF], pb[NPREF];

    PREF_DIFF(s0);
    WRITE_DIFF(s0 & 1);
    __syncthreads();

    double dacc = 0.0;

    for (int s = s0; s < s1; ++s) {
        int bu = s & 1;
        if (s + 1 < s1) PREF_DIFF(s + 1);      // issue loads early

        float acc[4][8];
        #pragma unroll
        for (int p = 0; p < 4; ++p)
            #pragma unroll
            for (int o = 0; o < 8; ++o) acc[p][o] = 0.f;

        #pragma unroll 1
        for (int cky = 0; cky < 21; ++cky) {
            int c = cky / 7, ky = cky % 7;
            const float* tr = &tile[bu][c][iy + ky][xb];
            float v[12];
            *(float4*)&v[0] = *(const float4*)&tr[0];
            *(float4*)&v[4] = *(const float4*)&tr[4];
            *(float4*)&v[8] = *(const float4*)&tr[8];
            const float* wrow = wT + cky*56;          // uniform, contiguous
            #pragma unroll
            for (int kx = 0; kx < 7; ++kx) {
                #pragma unroll
                for (int o = 0; o < 8; ++o) {
                    float wv = wrow[kx*8 + o];        // s_load -> SGPR
                    #pragma unroll
                    for (int p = 0; p < 4; ++p)
                        acc[p][o] += wv * v[p + kx];
                }
            }
        }

        #pragma unroll
        for (int p = 0; p < 4; ++p) {
            float ss = 0.f;
            #pragma unroll
            for (int o = 0; o < 8; ++o) {
                float d = acc[p][o] + PD_EPS;
                ss += d*d;
            }
            dacc += (double)sqrtf(ss);
        }

        if (s + 1 < s1) WRITE_DIFF(bu ^ 1);    // write-late (vmcnt hidden)
        __syncthreads();
    }

    #pragma unroll
    for (int off = 32; off > 0; off >>= 1)
        dacc += __shfl_down(dacc, off, 64);
    int wid = tid >> 6, lane = tid & 63;
    if (lane == 0) sred[wid] = dacc;
    __syncthreads();
    if (tid == 0) {
        double ssum = 0.0;
        for (int w = 0; w < 7; ++w) ssum += sred[w];
        scores[pair*2 + half] = ssum;
    }
}

// ---------------------------------------------------------------- sampling
__global__ void sample_kernel(char* __restrict__ ws)
{
    __shared__ double cum[BB][NP];
    const double* scores = (const double*)(ws + WS_SCORES);
    int* idxs = (int*)(ws + WS_IDX);
    int tid = threadIdx.x;                // 128
    if (tid < BB) {
        double tot = 0.0;
        for (int t = 0; t < NP; ++t)
            tot += sqrt(scores[(tid*NP + t)*2] + scores[(tid*NP + t)*2 + 1]);
        double run = 0.0;
        for (int t = 0; t < NP; ++t) {
            run += sqrt(scores[(tid*NP + t)*2] + scores[(tid*NP + t)*2 + 1]) / tot;
            cum[tid][t] = run;
        }
    }
    __syncthreads();
    {
        int b = tid / MM, m = tid % MM;
        double target = (double)((float)m / 15.f);
        int best = 0;
        double bv = fabs(cum[b][0] - target);
        for (int t = 1; t < NP; ++t) {
            double v = fabs(cum[b][t] - target);
            if (v < bv) { bv = v; best = t; }   // strict: first min wins
        }
        idxs[tid] = best;
    }
}

#define PREF_SRC(SS) do { int sbase = (SS)*TH - 3;                           \
    _Pragma("unroll")                                                        \
    for (int k = 0; k < NPREF; ++k) {                                        \
        int i = tid + k*NTH;                                                 \
        float va = 0.f;                                                      \
        if (i < STAGE_ELEMS) {                                               \
            int c  = i / ((TH+6)*TSTRIDE);                                   \
            int rem = i - c*((TH+6)*TSTRIDE);                                \
            int r  = rem / TSTRIDE;                                          \
            int cc = rem - r*TSTRIDE;                                        \
            int gr = sbase + r, gc = cc - 3;                                 \
            if ((unsigned)gr < HH && (unsigned)gc < WW)                      \
                va = src[c*HW + gr*WW + gc];                                 \
        }                                                                    \
        pa[k] = va;                                                          \
    }                                                                        \
} while (0)

#define WRITE_SRC(BUF) do {                                                  \
    float* dst = (float*)tile[BUF];                                          \
    _Pragma("unroll")                                                        \
    for (int k = 0; k < NPREF; ++k) {                                        \
        int i = tid + k*NTH;                                                 \
        if (i < STAGE_ELEMS) dst[i] = pa[k];                                 \
    }                                                                        \
} while (0)

// ---------------------------------------------------------------- resblock conv
// same double-buffered pipeline; combined 7x7 3->3; y -> d_out + BN partials
__global__ __launch_bounds__(NTH, 4) void resconv_kernel(
    const float* __restrict__ x, char* __restrict__ ws, float* __restrict__ out)
{
    __shared__ __align__(16) float tile[2][CIN][TH+6][TSTRIDE];
    __shared__ double sred[7][6];

    const float* wc    = (const float*)(ws + WS_WC);
    const float* bias2 = (const float*)(ws + WS_BIAS2);
    const int* idxs    = (const int*)(ws + WS_IDX);
    float* part        = (float*)(ws + WS_PART);

    int B = blockIdx.x;                        // 256 blocks
    int work = (B & 7) * 32 + (B >> 3);
    int n = work >> 1, half = work & 1;
    int b = n / MM;
    int l = idxs[n];
    const float* src = x + (size_t)(b*LL + l) * (CIN*HW);
    float* ybase = out + (size_t)n * (COUT*HW);

    int tid = threadIdx.x;
    int iy = tid / 28;
    int xb = (tid % 28) * 4;
    int s0 = half * 4, s1 = half ? 7 : 4;

    float bb0 = bias2[0], bb1 = bias2[1], bb2 = bias2[2];
    double sm0=0, sm1=0, sm2=0, sq0=0, sq1=0, sq2=0;

    float pa[NPREF];

    PREF_SRC(s0);
    WRITE_SRC(s0 & 1);
    __syncthreads();

    for (int s = s0; s < s1; ++s) {
        int bu = s & 1;
        if (s + 1 < s1) PREF_SRC(s + 1);

        float acc[4][3];
        #pragma unroll
        for (int p = 0; p < 4; ++p) { acc[p][0]=0.f; acc[p][1]=0.f; acc[p][2]=0.f; }

        #pragma unroll 1
        for (int cky = 0; cky < 21; ++cky) {
            int c = cky / 7, ky = cky % 7;
            const float* tr = &tile[bu][c][iy + ky][xb];
            float v[12];
            *(float4*)&v[0] = *(const float4*)&tr[0];
            *(float4*)&v[4] = *(const float4*)&tr[4];
            *(float4*)&v[8] = *(const float4*)&tr[8];
            const float* wrow = wc + cky*28;          // uniform, contiguous
            #pragma unroll
            for (int kx = 0; kx < 7; ++kx) {
                #pragma unroll
                for (int o = 0; o < 3; ++o) {
                    float wv = wrow[kx*4 + o];        // s_load -> SGPR
                    #pragma unroll
                    for (int p = 0; p < 4; ++p)
                        acc[p][o] += wv * v[p + kx];
                }
            }
        }

        int gy = s*TH + iy;
        float4 yv; float* pyv = (float*)&yv;
        #pragma unroll
        for (int p = 0; p < 4; ++p) {
            float val = acc[p][0] + bb0;
            pyv[p] = val; sm0 += val; sq0 += (double)val*val;
        }
        *(float4*)&ybase[0*HW + gy*WW + xb] = yv;
        #pragma unroll
        for (int p = 0; p < 4; ++p) {
            float val = acc[p][1] + bb1;
            pyv[p] = val; sm1 += val; sq1 += (double)val*val;
        }
        *(float4*)&ybase[1*HW + gy*WW + xb] = yv;
        #pragma unroll
        for (int p = 0; p < 4; ++p) {
            float val = acc[p][2] + bb2;
            pyv[p] = val; sm2 += val; sq2 += (double)val*val;
        }
        *(float4*)&ybase[2*HW + gy*WW + xb] = yv;

        if (s + 1 < s1) WRITE_SRC(bu ^ 1);
        __syncthreads();
    }

    double vals[6] = {sm0, sm1, sm2, sq0, sq1, sq2};
    #pragma unroll
    for (int j = 0; j < 6; ++j) {
        #pragma unroll
        for (int off = 32; off > 0; off >>= 1)
            vals[j] += __shfl_down(vals[j], off, 64);
    }
    int wid = tid >> 6, lane = tid & 63;
    if (lane == 0) {
        #pragma unroll
        for (int j = 0; j < 6; ++j) sred[wid][j] = vals[j];
    }
    __syncthreads();
    if (tid < 6) {
        double s = 0.0;
        for (int w = 0; w < 7; ++w) s += sred[w][tid];
        part[B*6 + tid] = (float)s;
    }
}

// ---------------------------------------------------------------- stats reduce
__global__ void statreduce_kernel(char* __restrict__ ws)
{
    const float* part = (const float*)(ws + WS_PART);
    float* stats = (float*)(ws + WS_STATS);
    int tid = threadIdx.x;            // 384: 6 cols x 64 lanes
    int j = tid >> 6, lane = tid & 63;
    double s = 0.0;
    for (int n = lane; n < 256; n += 64) s += (double)part[n*6 + j];
    #pragma unroll
    for (int off = 32; off > 0; off >>= 1)
        s += __shfl_down(s, off, 64);
    if (lane == 0) stats[j] = (float)s;
}

// ---------------------------------------------------------------- finalize
__global__ __launch_bounds__(256) void finalize_kernel(
    const float* __restrict__ x, const float* __restrict__ gamma,
    const float* __restrict__ beta, const char* __restrict__ ws,
    float* __restrict__ out)
{
    const float* stats = (const float*)(ws + WS_STATS);
    const int* idxs    = (const int*)(ws + WS_IDX);
    int i4 = blockIdx.x * 256 + threadIdx.x;
    int i  = i4 * 4;
    int n  = i / (COUT*HW);
    int c  = (i / HW) % COUT;
    int hw = i % HW;
    int b  = n / MM;
    int l  = idxs[n];
    const float Ninv = 1.f / (float)(BB*MM*HW);
    float mean  = stats[c] * Ninv;
    float var   = stats[3+c] * Ninv - mean*mean;
    float scale = gamma[c] / sqrtf(var + BN_EPS);
    float shift = beta[c] - mean*scale;
    float4 y  = *(const float4*)&out[i];
    float4 xv = *(const float4*)&x[((size_t)(b*LL + l)*CIN + c)*HW + hw];
    float4 r;
    r.x = xv.x + fmaxf(y.x*scale + shift, 0.f);
    r.y = xv.y + fmaxf(y.y*scale + shift, 0.f);
    r.z = xv.z + fmaxf(y.z*scale + shift, 0.f);
    r.w = xv.w + fmaxf(y.w*scale + shift, 0.f);
    *(float4*)&out[i] = r;
}

// ---------------------------------------------------------------- launch
extern "C" void kernel_launch(void* const* d_in, const int* in_sizes, int n_in,
                              void* d_out, int out_size, void* d_ws, size_t ws_size,
                              hipStream_t stream)
{
    const float* x       = (const float*)d_in[0];
    const float* conv_w  = (const float*)d_in[1];
    const float* conv_b  = (const float*)d_in[2];
    const float* bneck_w = (const float*)d_in[3];
    const float* gamma   = (const float*)d_in[4];
    const float* beta    = (const float*)d_in[5];
    float* out = (float*)d_out;
    char* ws   = (char*)d_ws;

    prep_kernel<<<1, 256, 0, stream>>>(conv_w, conv_b, bneck_w, ws);
    score_kernel<<<BB*NP*2, NTH, 0, stream>>>(x, ws);
    sample_kernel<<<1, 128, 0, stream>>>(ws);
    resconv_kernel<<<BB*MM*2, NTH, 0, stream>>>(x, ws, out);
    statreduce_kernel<<<1, 384, 0, stream>>>(ws);
    int total4 = (BB*MM*COUT*HW) / 4;
    finalize_kernel<<<total4 / 256, 256, 0, stream>>>(x, gamma, beta, ws, out);
}

// Round 6
// 238.514 us; speedup vs baseline: 1.6062x; 1.0256x over previous
//
#include <hip/hip_runtime.h>
#include <math.h>

#define BB 8
#define LL 64
#define NP 63          // frame pairs per batch
#define MM 16          // sampled frames
#define HH 112
#define WW 112
#define HW (HH*WW)
#define CIN 3
#define CMID 8
#define COUT 3
#define TH 16          // stripe rows
#define TSTRIDE 120    // WW + 8 pad
#define NTH 448        // 16 rows x 28 col-groups of 4 px
#define STAGE_ELEMS (CIN*(TH+6)*TSTRIDE)   // 7920
#define NPREF 18                            // ceil(7920/448)

// workspace byte offsets
#define WS_SCORES 0        // double[504*2]
#define WS_IDX    16384    // int[128]
#define WS_WT     17408    // float[1176]  score weights [c*7+ky][kx][o=8]
#define WS_WC     22528    // float[588]   combined weights [c*7+ky][kx][o pad4]
#define WS_BIAS2  24960    // float[4]
#define WS_PART   25088    // float[256*6]
#define WS_STATS  37376    // float[6]

#define PD_EPS 1e-6f
#define BN_EPS 1e-5f

// ---------------------------------------------------------------- prep
__global__ void prep_kernel(const float* __restrict__ cw, const float* __restrict__ cb,
                            const float* __restrict__ bw, char* __restrict__ ws)
{
    float* wT = (float*)(ws + WS_WT);
    float* wc = (float*)(ws + WS_WC);
    float* b2 = (float*)(ws + WS_BIAS2);
    int tid = threadIdx.x;
    for (int i = tid; i < CIN*49*CMID; i += 256) {
        int cky = i / 56, r = i % 56, kx = r / 8, o = r % 8;
        int c = cky / 7, ky = cky % 7;
        wT[i] = cw[((o*CIN + c)*7 + ky)*7 + kx];
    }
    for (int i = tid; i < CIN*49; i += 256) {
        int c = i / 49, ky = (i / 7) % 7, kx = i % 7;
        for (int o = 0; o < COUT; ++o) {
            float s = 0.f;
            for (int m = 0; m < CMID; ++m)
                s += bw[o*CMID + m] * cw[((m*CIN + c)*7 + ky)*7 + kx];
            wc[(c*7 + ky)*28 + kx*4 + o] = s;
        }
        wc[(c*7 + ky)*28 + kx*4 + 3] = 0.f;
    }
    if (tid < COUT) {
        float s = 0.f;
        for (int m = 0; m < CMID; ++m) s += bw[tid*CMID + m] * cb[m];
        b2[tid] = s;
    }
}

// prefetch next stripe's diff elements into registers (issue-early)
#define PREF_DIFF(SS) do { int sbase = (SS)*TH - 3;                          \
    _Pragma("unroll")                                                        \
    for (int k = 0; k < NPREF; ++k) {                                        \
        int i = tid + k*NTH;                                                 \
        float va = 0.f, vb = 0.f;                                            \
        if (i < STAGE_ELEMS) {                                               \
            int c  = i / ((TH+6)*TSTRIDE);                                   \
            int rem = i - c*((TH+6)*TSTRIDE);                                \
            int r  = rem / TSTRIDE;                                          \
            int cc = rem - r*TSTRIDE;                                        \
            int gr = sbase + r, gc = cc - 3;                                 \
            if ((unsigned)gr < HH && (unsigned)gc < WW) {                    \
                int off = c*HW + gr*WW + gc;                                 \
                va = x0[off]; vb = x1[off];                                  \
            }                                                                \
        }                                                                    \
        pa[k] = va; pb[k] = vb;                                              \
    }                                                                        \
} while (0)

#define WRITE_DIFF(BUF) do {                                                 \
    float* dst = (float*)tile[BUF];                                          \
    _Pragma("unroll")                                                        \
    for (int k = 0; k < NPREF; ++k) {                                        \
        int i = tid + k*NTH;                                                 \
        if (i < STAGE_ELEMS) dst[i] = pa[k] - pb[k];                         \
    }                                                                        \
} while (0)

// ---------------------------------------------------------------- scores
// 2 blocks per pair (stripes 0-3 / 4-6). Double-buffered LDS diff tile with
// register prefetch: loads for stripe s+1 issue BEFORE the FMA phase of s,
// regs->LDS write after it (vmcnt drain hidden under compute). One barrier
// per stripe. Weights via contiguous uniform s_load -> SGPR FMA operands.
// NOTE: no min-waves arg in launch_bounds — (448,4) forced a 64-VGPR cap
// (7-wave blocks -> 6 waves/EU worst case -> 85 -> granule 64) and spilled
// the prefetch registers to scratch (r5: WRITE_SIZE 3.4MB, VGPR=64).
__global__ __launch_bounds__(NTH) void score_kernel(
    const float* __restrict__ x, char* __restrict__ ws)
{
    __shared__ __align__(16) float tile[2][CIN][TH+6][TSTRIDE];  // 63360 B
    __shared__ double sred[7];
    const float* wT = (const float*)(ws + WS_WT);
    double* scores  = (double*)(ws + WS_SCORES);

    int B = blockIdx.x;                        // 1008 blocks, 1008%8==0
    int work = (B & 7) * 126 + (B >> 3);       // XCD-chunked swizzle
    int pair = work >> 1, half = work & 1;
    int b = pair / NP, t = pair % NP;
    const float* x0 = x + (size_t)(b*LL + t) * (CIN*HW);
    const float* x1 = x0 + CIN*HW;

    int tid = threadIdx.x;
    int iy = tid / 28;
    int xb = (tid % 28) * 4;
    int s0 = half * 4, s1 = half ? 7 : 4;

    float pa[NPREF], pb[NPREF];

    PREF_DIFF(s0);
    WRITE_DIFF(s0 & 1);
    __syncthreads();

    double dacc = 0.0;

    for (int s = s0; s < s1; ++s) {
        int bu = s & 1;
        if (s + 1 < s1) PREF_DIFF(s + 1);      // issue loads early

        float acc[4][8];
        #pragma unroll
        for (int p = 0; p < 4; ++p)
            #pragma unroll
            for (int o = 0; o < 8; ++o) acc[p][o] = 0.f;

        #pragma unroll 1
        for (int cky = 0; cky < 21; ++cky) {
            int c = cky / 7, ky = cky % 7;
            const float* tr = &tile[bu][c][iy + ky][xb];
            float v[12];
            *(float4*)&v[0] = *(const float4*)&tr[0];
            *(float4*)&v[4] = *(const float4*)&tr[4];
            *(float4*)&v[8] = *(const float4*)&tr[8];
            const float* wrow = wT + cky*56;          // uniform, contiguous
            #pragma unroll
            for (int kx = 0; kx < 7; ++kx) {
                #pragma unroll
                for (int o = 0; o < 8; ++o) {
                    float wv = wrow[kx*8 + o];        // s_load -> SGPR
                    #pragma unroll
                    for (int p = 0; p < 4; ++p)
                        acc[p][o] += wv * v[p + kx];
                }
            }
        }

        #pragma unroll
        for (int p = 0; p < 4; ++p) {
            float ss = 0.f;
            #pragma unroll
            for (int o = 0; o < 8; ++o) {
                float d = acc[p][o] + PD_EPS;
                ss += d*d;
            }
            dacc += (double)sqrtf(ss);
        }

        if (s + 1 < s1) WRITE_DIFF(bu ^ 1);    // write-late (vmcnt hidden)
        __syncthreads();
    }

    #pragma unroll
    for (int off = 32; off > 0; off >>= 1)
        dacc += __shfl_down(dacc, off, 64);
    int wid = tid >> 6, lane = tid & 63;
    if (lane == 0) sred[wid] = dacc;
    __syncthreads();
    if (tid == 0) {
        double ssum = 0.0;
        for (int w = 0; w < 7; ++w) ssum += sred[w];
        scores[pair*2 + half] = ssum;
    }
}

// ---------------------------------------------------------------- sampling
__global__ void sample_kernel(char* __restrict__ ws)
{
    __shared__ double cum[BB][NP];
    const double* scores = (const double*)(ws + WS_SCORES);
    int* idxs = (int*)(ws + WS_IDX);
    int tid = threadIdx.x;                // 128
    if (tid < BB) {
        double tot = 0.0;
        for (int t = 0; t < NP; ++t)
            tot += sqrt(scores[(tid*NP + t)*2] + scores[(tid*NP + t)*2 + 1]);
        double run = 0.0;
        for (int t = 0; t < NP; ++t) {
            run += sqrt(scores[(tid*NP + t)*2] + scores[(tid*NP + t)*2 + 1]) / tot;
            cum[tid][t] = run;
        }
    }
    __syncthreads();
    {
        int b = tid / MM, m = tid % MM;
        double target = (double)((float)m / 15.f);
        int best = 0;
        double bv = fabs(cum[b][0] - target);
        for (int t = 1; t < NP; ++t) {
            double v = fabs(cum[b][t] - target);
            if (v < bv) { bv = v; best = t; }   // strict: first min wins
        }
        idxs[tid] = best;
    }
}

#define PREF_SRC(SS) do { int sbase = (SS)*TH - 3;                           \
    _Pragma("unroll")                                                        \
    for (int k = 0; k < NPREF; ++k) {                                        \
        int i = tid + k*NTH;                                                 \
        float va = 0.f;                                                      \
        if (i < STAGE_ELEMS) {                                               \
            int c  = i / ((TH+6)*TSTRIDE);                                   \
            int rem = i - c*((TH+6)*TSTRIDE);                                \
            int r  = rem / TSTRIDE;                                          \
            int cc = rem - r*TSTRIDE;                                        \
            int gr = sbase + r, gc = cc - 3;                                 \
            if ((unsigned)gr < HH && (unsigned)gc < WW)                      \
                va = src[c*HW + gr*WW + gc];                                 \
        }                                                                    \
        pa[k] = va;                                                          \
    }                                                                        \
} while (0)

#define WRITE_SRC(BUF) do {                                                  \
    float* dst = (float*)tile[BUF];                                          \
    _Pragma("unroll")                                                        \
    for (int k = 0; k < NPREF; ++k) {                                        \
        int i = tid + k*NTH;                                                 \
        if (i < STAGE_ELEMS) dst[i] = pa[k];                                 \
    }                                                                        \
} while (0)

// ---------------------------------------------------------------- resblock conv
// same double-buffered pipeline; combined 7x7 3->3; y -> d_out + BN partials
__global__ __launch_bounds__(NTH) void resconv_kernel(
    const float* __restrict__ x, char* __restrict__ ws, float* __restrict__ out)
{
    __shared__ __align__(16) float tile[2][CIN][TH+6][TSTRIDE];
    __shared__ double sred[7][6];

    const float* wc    = (const float*)(ws + WS_WC);
    const float* bias2 = (const float*)(ws + WS_BIAS2);
    const int* idxs    = (const int*)(ws + WS_IDX);
    float* part        = (float*)(ws + WS_PART);

    int B = blockIdx.x;                        // 256 blocks
    int work = (B & 7) * 32 + (B >> 3);
    int n = work >> 1, half = work & 1;
    int b = n / MM;
    int l = idxs[n];
    const float* src = x + (size_t)(b*LL + l) * (CIN*HW);
    float* ybase = out + (size_t)n * (COUT*HW);

    int tid = threadIdx.x;
    int iy = tid / 28;
    int xb = (tid % 28) * 4;
    int s0 = half * 4, s1 = half ? 7 : 4;

    float bb0 = bias2[0], bb1 = bias2[1], bb2 = bias2[2];
    double sm0=0, sm1=0, sm2=0, sq0=0, sq1=0, sq2=0;

    float pa[NPREF];

    PREF_SRC(s0);
    WRITE_SRC(s0 & 1);
    __syncthreads();

    for (int s = s0; s < s1; ++s) {
        int bu = s & 1;
        if (s + 1 < s1) PREF_SRC(s + 1);

        float acc[4][3];
        #pragma unroll
        for (int p = 0; p < 4; ++p) { acc[p][0]=0.f; acc[p][1]=0.f; acc[p][2]=0.f; }

        #pragma unroll 1
        for (int cky = 0; cky < 21; ++cky) {
            int c = cky / 7, ky = cky % 7;
            const float* tr = &tile[bu][c][iy + ky][xb];
            float v[12];
            *(float4*)&v[0] = *(const float4*)&tr[0];
            *(float4*)&v[4] = *(const float4*)&tr[4];
            *(float4*)&v[8] = *(const float4*)&tr[8];
            const float* wrow = wc + cky*28;          // uniform, contiguous
            #pragma unroll
            for (int kx = 0; kx < 7; ++kx) {
                #pragma unroll
                for (int o = 0; o < 3; ++o) {
                    float wv = wrow[kx*4 + o];        // s_load -> SGPR
                    #pragma unroll
                    for (int p = 0; p < 4; ++p)
                        acc[p][o] += wv * v[p + kx];
                }
            }
        }

        int gy = s*TH + iy;
        float4 yv; float* pyv = (float*)&yv;
        #pragma unroll
        for (int p = 0; p < 4; ++p) {
            float val = acc[p][0] + bb0;
            pyv[p] = val; sm0 += val; sq0 += (double)val*val;
        }
        *(float4*)&ybase[0*HW + gy*WW + xb] = yv;
        #pragma unroll
        for (int p = 0; p < 4; ++p) {
            float val = acc[p][1] + bb1;
            pyv[p] = val; sm1 += val; sq1 += (double)val*val;
        }
        *(float4*)&ybase[1*HW + gy*WW + xb] = yv;
        #pragma unroll
        for (int p = 0; p < 4; ++p) {
            float val = acc[p][2] + bb2;
            pyv[p] = val; sm2 += val; sq2 += (double)val*val;
        }
        *(float4*)&ybase[2*HW + gy*WW + xb] = yv;

        if (s + 1 < s1) WRITE_SRC(bu ^ 1);
        __syncthreads();
    }

    double vals[6] = {sm0, sm1, sm2, sq0, sq1, sq2};
    #pragma unroll
    for (int j = 0; j < 6; ++j) {
        #pragma unroll
        for (int off = 32; off > 0; off >>= 1)
            vals[j] += __shfl_down(vals[j], off, 64);
    }
    int wid = tid >> 6, lane = tid & 63;
    if (lane == 0) {
        #pragma unroll
        for (int j = 0; j < 6; ++j) sred[wid][j] = vals[j];
    }
    __syncthreads();
    if (tid < 6) {
        double s = 0.0;
        for (int w = 0; w < 7; ++w) s += sred[w][tid];
        part[B*6 + tid] = (float)s;
    }
}

// ---------------------------------------------------------------- stats reduce
__global__ void statreduce_kernel(char* __restrict__ ws)
{
    const float* part = (const float*)(ws + WS_PART);
    float* stats = (float*)(ws + WS_STATS);
    int tid = threadIdx.x;            // 384: 6 cols x 64 lanes
    int j = tid >> 6, lane = tid & 63;
    double s = 0.0;
    for (int n = lane; n < 256; n += 64) s += (double)part[n*6 + j];
    #pragma unroll
    for (int off = 32; off > 0; off >>= 1)
        s += __shfl_down(s, off, 64);
    if (lane == 0) stats[j] = (float)s;
}

// ---------------------------------------------------------------- finalize
__global__ __launch_bounds__(256) void finalize_kernel(
    const float* __restrict__ x, const float* __restrict__ gamma,
    const float* __restrict__ beta, const char* __restrict__ ws,
    float* __restrict__ out)
{
    const float* stats = (const float*)(ws + WS_STATS);
    const int* idxs    = (const int*)(ws + WS_IDX);
    int i4 = blockIdx.x * 256 + threadIdx.x;
    int i  = i4 * 4;
    int n  = i / (COUT*HW);
    int c  = (i / HW) % COUT;
    int hw = i % HW;
    int b  = n / MM;
    int l  = idxs[n];
    const float Ninv = 1.f / (float)(BB*MM*HW);
    float mean  = stats[c] * Ninv;
    float var   = stats[3+c] * Ninv - mean*mean;
    float scale = gamma[c] / sqrtf(var + BN_EPS);
    float shift = beta[c] - mean*scale;
    float4 y  = *(const float4*)&out[i];
    float4 xv = *(const float4*)&x[((size_t)(b*LL + l)*CIN + c)*HW + hw];
    float4 r;
    r.x = xv.x + fmaxf(y.x*scale + shift, 0.f);
    r.y = xv.y + fmaxf(y.y*scale + shift, 0.f);
    r.z = xv.z + fmaxf(y.z*scale + shift, 0.f);
    r.w = xv.w + fmaxf(y.w*scale + shift, 0.f);
    *(float4*)&out[i] = r;
}

// ---------------------------------------------------------------- launch
extern "C" void kernel_launch(void* const* d_in, const int* in_sizes, int n_in,
                              void* d_out, int out_size, void* d_ws, size_t ws_size,
                              hipStream_t stream)
{
    const float* x       = (const float*)d_in[0];
    const float* conv_w  = (const float*)d_in[1];
    const float* conv_b  = (const float*)d_in[2];
    const float* bneck_w = (const float*)d_in[3];
    const float* gamma   = (const float*)d_in[4];
    const float* beta    = (const float*)d_in[5];
    float* out = (float*)d_out;
    char* ws   = (char*)d_ws;

    prep_kernel<<<1, 256, 0, stream>>>(conv_w, conv_b, bneck_w, ws);
    score_kernel<<<BB*NP*2, NTH, 0, stream>>>(x, ws);
    sample_kernel<<<1, 128, 0, stream>>>(ws);
    resconv_kernel<<<BB*MM*2, NTH, 0, stream>>>(x, ws, out);
    statreduce_kernel<<<1, 384, 0, stream>>>(ws);
    int total4 = (BB*MM*COUT*HW) / 4;
    finalize_kernel<<<total4 / 256, 256, 0, stream>>>(x, gamma, beta, ws, out);
}